// Round 14
// baseline (155.477 us; speedup 1.0000x reference)
//
#include <hip/hip_runtime.h>
#include <hip/hip_bf16.h>

#define B_ 4
#define H_ 16
#define N_ 2048
#define D_ 64
#define BM 128   // q-rows per WG (32 per wave, 4 waves)

typedef __bf16 bf16;
typedef bf16 bf16x4 __attribute__((ext_vector_type(4)));
typedef bf16 bf16x8 __attribute__((ext_vector_type(8)));
typedef float f32x16 __attribute__((ext_vector_type(16)));
typedef unsigned u32x2 __attribute__((ext_vector_type(2)));
typedef unsigned u32x4 __attribute__((ext_vector_type(4)));

#define SCALE_LOG2E 0.18033688011112042f  // (1/sqrt(64)) * log2(e)

#define GBL(p) ((const __attribute__((address_space(1))) void*)(p))
#define LDS(p) ((__attribute__((address_space(3))) void*)(p))

// Per (b, kv-tile T of 64): 16 KB image in per-lane FRAGMENT ORDER for 32x32x16 MFMA.
//   K half  [0,8KB):  unit p=(mt*4+ks)*64+ln : A-frag K[kv=T*64+mt*32+(ln&31)][d=ks*16+(ln>>5)*8 ..+8]
//   V half  [8,16KB): unit p=(mt*4+ks)*64+ln : A-frag V^T[d=mt*32+(ln&31)][kv=T*64+ks*16+(ln>>5)*8 ..+8]
//
// Round-14: 2 blocks per tile (256 blocks total = 1/CU, was 128 = 0.5/CU:
// half the GPU sat idle). part 0 = K copy (no LDS, no barrier); part 1 =
// V transpose via LDS (coalesced float4 row reads -> padded LDS ->
// fragment-order reads -> coalesced bf16x8 store). attn_fwd untouched.
__global__ __launch_bounds__(256) void convert_kv(const float* __restrict__ k,
                                                  const float* __restrict__ v,
                                                  bf16* __restrict__ img) {
    const int tile = blockIdx.x >> 1;             // b*32 + T
    const int part = blockIdx.x & 1;              // 0: K half  1: V half
    const int b = tile >> 5, T = tile & 31;
    const int tid = threadIdx.x;                  // 0..255
    bf16* timg = img + (size_t)tile * 8192;       // 16 KB per tile

    if (part == 0) {
        // --- K half: direct, coalesced both sides; 2 units per thread ---
        #pragma unroll
        for (int uu = 0; uu < 2; ++uu) {
            const int t = tid + uu * 256;         // unit 0..511
            const int mtks = t >> 6;
            const int ln   = t & 63;
            const int mt = mtks >> 2, ks = mtks & 3;
            const int kvr = T * 64 + mt * 32 + (ln & 31);
            const int d0  = ks * 16 + (ln >> 5) * 8;
            const float* src = k + ((size_t)b * N_ + kvr) * D_ + d0;
            float4 a = *(const float4*)src;
            float4 c = *(const float4*)(src + 4);
            bf16x8 o;
            o[0] = (bf16)a.x; o[1] = (bf16)a.y; o[2] = (bf16)a.z; o[3] = (bf16)a.w;
            o[4] = (bf16)c.x; o[5] = (bf16)c.y; o[6] = (bf16)c.z; o[7] = (bf16)c.w;
            *(bf16x8*)(timg + t * 8) = o;
        }
    } else {
        __shared__ bf16 VT[64][66];               // stride 66 elems (132 B)
        // --- V phase 1: coalesced row load -> LDS bf16; 2 chunk-units/thread ---
        #pragma unroll
        for (int uu = 0; uu < 2; ++uu) {
            const int u  = tid + uu * 256;        // 0..511
            const int kv = u >> 3;                // 0..63 (tile-local row)
            const int c8 = (u & 7) * 8;           // 0..56
            const float* src = v + ((size_t)b * N_ + T * 64 + kv) * D_ + c8;
            float4 a = *(const float4*)src;
            float4 c = *(const float4*)(src + 4);
            VT[kv][c8 + 0] = (bf16)a.x; VT[kv][c8 + 1] = (bf16)a.y;
            VT[kv][c8 + 2] = (bf16)a.z; VT[kv][c8 + 3] = (bf16)a.w;
            VT[kv][c8 + 4] = (bf16)c.x; VT[kv][c8 + 5] = (bf16)c.y;
            VT[kv][c8 + 6] = (bf16)c.z; VT[kv][c8 + 7] = (bf16)c.w;
        }
        __syncthreads();
        // --- V phase 2: fragment-order read, coalesced store; 2 units/thread ---
        #pragma unroll
        for (int uu = 0; uu < 2; ++uu) {
            const int t = tid + uu * 256;         // unit 0..511
            const int mtks = t >> 6;
            const int ln   = t & 63;
            const int mt = mtks >> 2, ks = mtks & 3;
            const int d   = mt * 32 + (ln & 31);
            const int kv0 = ks * 16 + (ln >> 5) * 8;  // tile-local
            bf16x8 o;
            #pragma unroll
            for (int j = 0; j < 8; ++j) o[j] = VT[kv0 + j][d];
            *(bf16x8*)(timg + 4096 + t * 8) = o;
        }
    }
}

static __device__ inline bf16x4 pack4(float a, float b, float c, float d) {
    bf16x4 r; r[0] = (bf16)a; r[1] = (bf16)b; r[2] = (bf16)c; r[3] = (bf16)d; return r;
}

// C->B half-wave exchange via v_permlane32_swap_b32. For (p,q) = swap(L,H):
//   p = {L.row0, H.row0}  == (half ? xhi : lo)
//   q = {L.row1, H.row1}  == (half ? hi  : xlo)
static __device__ inline bf16x8 cswap(bf16x4 lo, bf16x4 hi) {
    u32x2 l = __builtin_bit_cast(u32x2, lo);
    u32x2 h = __builtin_bit_cast(u32x2, hi);
    u32x2 r0 = __builtin_amdgcn_permlane32_swap(l[0], h[0], false, false);
    u32x2 r1 = __builtin_amdgcn_permlane32_swap(l[1], h[1], false, false);
    u32x4 o; o[0] = r0[0]; o[1] = r1[0]; o[2] = r0[1]; o[3] = r1[1];
    return __builtin_bit_cast(bf16x8, o);
}

// Flash attention, 32x32x16 MFMA, S^T/O^T orientation, P in registers.
//
// CHAMPION (= R8/R13, 82.5us attn). One-tile software pipeline: body =
// { S-MFMAs(tile t) || softmax+PV(tile t-1) } so exp2 never depends on
// just-issued MFMAs; S consumed a full iteration (~500cy) later. 3-slot
// LDS ring (mod-3: DMA write slot provably != both read slots).
//
// Session evidence (14 variants): sharp local optimum.
//  - pipeline (this): -10% vs the ~90us plateau. The ONLY attn win.
//  - occupancy 8->16 w/CU: null. Free-running/no barriers: null.
//  - reg prefetch depth: -7%. setprio: -3%. ones-MFMA denom: -8% here
//    (accL = 8-touch/tile serial MFMA chain). 1 S-chain: -6%.
//  - PV chain split (+32 regs): -5% (occupancy). Body x2 (+state): -7%
//    (spill). Per-wave state exactly fills the 2-wave/SIMD band.
__global__ __launch_bounds__(256, 2) void attn_fwd(const float* __restrict__ q,
                                                   const bf16* __restrict__ img,
                                                   float* __restrict__ out) {
    __shared__ __align__(16) bf16 KV3[3][8192];   // 3-slot ring, 48 KB

    const int tid  = threadIdx.x;
    const int lane = tid & 63;
    const int wv   = tid >> 6;          // 0..3
    const int half = lane >> 5;
    const int l31  = lane & 31;

    const int bh = blockIdx.y;
    const int b  = bh >> 4;
    const int q0 = blockIdx.x * BM + wv * 32;

    const bf16* tiles = img + (size_t)b * 32 * 8192;

    // Q frags (B-layout for S^T: n=q=l31, k=d=ks*16+half*8+j), pre-scaled
    bf16x8 qf[4];
    #pragma unroll
    for (int ks = 0; ks < 4; ++ks) {
        const float* src = q + ((size_t)bh * N_ + q0 + l31) * D_ + ks * 16 + half * 8;
        float4 a = *(const float4*)src;
        float4 c = *(const float4*)(src + 4);
        bf16x8 pk;
        pk[0] = (bf16)(a.x * SCALE_LOG2E); pk[1] = (bf16)(a.y * SCALE_LOG2E);
        pk[2] = (bf16)(a.z * SCALE_LOG2E); pk[3] = (bf16)(a.w * SCALE_LOG2E);
        pk[4] = (bf16)(c.x * SCALE_LOG2E); pk[5] = (bf16)(c.y * SCALE_LOG2E);
        pk[6] = (bf16)(c.z * SCALE_LOG2E); pk[7] = (bf16)(c.w * SCALE_LOG2E);
        qf[ks] = pk;
    }

    f32x16 acc[2] = {{}, {}};           // O^T tiles [mt_d] (unnormalized)
    float lacc = 0.f;

    auto issue_dma = [&](int t, int sl) {
        const bf16* g = tiles + (size_t)t * 8192;
        #pragma unroll
        for (int j = 0; j < 4; ++j) {
            const int c = wv * 4 + j;             // 1 KB chunk 0..15
            __builtin_amdgcn_global_load_lds(GBL(g + c * 512 + lane * 8),
                                             LDS(&KV3[sl][c * 512]), 16, 0, 0);
        }
    };

    // S^T(tile it) = K Q^T into s: K frags JIT from ring slot it%3.
    // Two interleaved s-chains (R9: one chain = -5us).
    auto computeS = [&](int it, f32x16 (&s)[2]) {
        const bf16* bp = &KV3[it % 3][0];
        s[0] = f32x16{}; s[1] = f32x16{};
        #pragma unroll
        for (int ks = 0; ks < 4; ++ks) {
            bf16x8 k0 = *(const bf16x8*)&bp[((0 * 4 + ks) * 64 + lane) * 8];
            bf16x8 k1 = *(const bf16x8*)&bp[((1 * 4 + ks) * 64 + lane) * 8];
            s[0] = __builtin_amdgcn_mfma_f32_32x32x16_bf16(k0, qf[ks], s[0], 0, 0, 0);
            s[1] = __builtin_amdgcn_mfma_f32_32x32x16_bf16(k1, qf[ks], s[1], 0, 0, 0);
        }
    };
    // softmax + PV for tile it (V frags JIT from ring slot it%3).
    // Denominator on VALU (R11: ones-MFMA makes an 8-touch serial chain).
    auto softpv = [&](int it, const f32x16 (&s)[2]) {
        const bf16* vp = &KV3[it % 3][4096];
        #pragma unroll
        for (int mt = 0; mt < 2; ++mt) {
            #pragma unroll
            for (int sp = 0; sp < 2; ++sp) {
                const int g = mt * 2 + sp;        // kv k-step 0..3
                bf16x8 v0 = *(const bf16x8*)&vp[((0 * 4 + g) * 64 + lane) * 8];
                bf16x8 v1 = *(const bf16x8*)&vp[((1 * 4 + g) * 64 + lane) * 8];
                float pv8[8];
                #pragma unroll
                for (int r = 0; r < 8; ++r) pv8[r] = __builtin_amdgcn_exp2f(s[mt][8 * sp + r]);
                lacc += ((pv8[0] + pv8[1]) + (pv8[2] + pv8[3]))
                      + ((pv8[4] + pv8[5]) + (pv8[6] + pv8[7]));
                bf16x4 lo = pack4(pv8[0], pv8[1], pv8[2], pv8[3]);
                bf16x4 hi = pack4(pv8[4], pv8[5], pv8[6], pv8[7]);
                bf16x8 bfrag = cswap(lo, hi);
                acc[0] = __builtin_amdgcn_mfma_f32_32x32x16_bf16(v0, bfrag, acc[0], 0, 0, 0);
                acc[1] = __builtin_amdgcn_mfma_f32_32x32x16_bf16(v1, bfrag, acc[1], 0, 0, 0);
            }
        }
    };

    f32x16 sA[2], sB[2];

    // prologue: fill slot 0, start slot 1, compute S(0)
    issue_dma(0, 0);
    __syncthreads();                              // DMA(0) complete
    issue_dma(1, 1);
    computeS(0, sA);

    // pipelined main loop: pairs (it, it+1) for it = 1,3,...,29
    #pragma unroll 1
    for (int it = 1; it < 31; it += 2) {
        __syncthreads();                          // DMA(it) complete; prev reads done
        issue_dma(it + 1, (it + 1) % 3);          // overwrites tile it-2 (consumed)
        computeS(it, sB);                         // MFMA pipe: S(it)
        softpv(it - 1, sA);                       // VALU/trans+MFMA: tile it-1
        __syncthreads();                          // DMA(it+1) complete
        issue_dma(it + 2, (it + 2) % 3);          // it+2 <= 31
        computeS(it + 1, sA);
        softpv(it, sB);
    }
    // tail: S(31) + softmax(30), then softmax(31)
    __syncthreads();                              // DMA(31) complete
    computeS(31, sB);
    softpv(30, sA);
    softpv(31, sB);

    // epilogue: denominator = own + partner half-wave partial; store float4
    float l = lacc + __shfl_xor(lacc, 32);
    float inv = 1.0f / l;
    const int qrow = q0 + l31;
    float* dst = out + ((size_t)bh * N_ + qrow) * D_ + 4 * half;
    #pragma unroll
    for (int mt = 0; mt < 2; ++mt)
        #pragma unroll
        for (int rq = 0; rq < 4; ++rq) {
            float4 o;
            o.x = acc[mt][4 * rq + 0] * inv;
            o.y = acc[mt][4 * rq + 1] * inv;
            o.z = acc[mt][4 * rq + 2] * inv;
            o.w = acc[mt][4 * rq + 3] * inv;
            *(float4*)(dst + mt * 32 + 8 * rq) = o;   // d = mt*32 + 8*rq + 4*half
        }
}

extern "C" void kernel_launch(void* const* d_in, const int* in_sizes, int n_in,
                              void* d_out, int out_size, void* d_ws, size_t ws_size,
                              hipStream_t stream) {
    const float* q = (const float*)d_in[0];
    const float* k = (const float*)d_in[1];
    const float* v = (const float*)d_in[2];
    float* out = (float*)d_out;

    bf16* img = (bf16*)d_ws;                      // 128 tiles x 16 KB = 2 MB

    convert_kv<<<B_ * 64, 256, 0, stream>>>(k, v, img);
    dim3 grid(N_ / BM, B_ * H_);
    attn_fwd<<<grid, 256, 0, stream>>>(q, img, out);
}

// Round 15
// 153.658 us; speedup vs baseline: 1.0118x; 1.0118x over previous
//
#include <hip/hip_runtime.h>
#include <hip/hip_bf16.h>

#define B_ 4
#define H_ 16
#define N_ 2048
#define D_ 64
#define BM 128   // q-rows per WG (32 per wave, 4 waves)

typedef __bf16 bf16;
typedef bf16 bf16x4 __attribute__((ext_vector_type(4)));
typedef bf16 bf16x8 __attribute__((ext_vector_type(8)));
typedef float f32x16 __attribute__((ext_vector_type(16)));
typedef unsigned u32x2 __attribute__((ext_vector_type(2)));
typedef unsigned u32x4 __attribute__((ext_vector_type(4)));

#define SCALE_LOG2E 0.18033688011112042f  // (1/sqrt(64)) * log2(e)

#define GBL(p) ((const __attribute__((address_space(1))) void*)(p))
#define LDS(p) ((__attribute__((address_space(3))) void*)(p))

// Per (b, kv-tile T of 64): 16 KB image in per-lane FRAGMENT ORDER for 32x32x16 MFMA.
//   K half  [0,8KB):  unit p=(mt*4+ks)*64+ln : A-frag K[kv=T*64+mt*32+(ln&31)][d=ks*16+(ln>>5)*8 ..+8]
//   V half  [8,16KB): unit p=(mt*4+ks)*64+ln : A-frag V^T[d=mt*32+(ln&31)][kv=T*64+ks*16+(ln>>5)*8 ..+8]
// V transpose via LDS: coalesced float4 row reads -> padded LDS -> fragment-order
// reads -> coalesced bf16x8 store. One block per tile. (R14 tested a 2-block
// split: null -> convert_kv is not on the critical path; this is the R13 form.)
__global__ __launch_bounds__(512) void convert_kv(const float* __restrict__ k,
                                                  const float* __restrict__ v,
                                                  bf16* __restrict__ img) {
    __shared__ bf16 VT[64][66];                   // stride 66 elems (132 B)
    const int tile = blockIdx.x;                  // b*32 + T
    const int b = tile >> 5, T = tile & 31;
    const int t = threadIdx.x;                    // 0..511 == unit id
    bf16* timg = img + (size_t)tile * 8192;       // 16 KB per tile

    const int mtks = t >> 6;
    const int ln   = t & 63;
    const int mt = mtks >> 2, ks = mtks & 3;

    // --- K half: direct, coalesced both sides ---
    {
        const int kvr = T * 64 + mt * 32 + (ln & 31);
        const int d0  = ks * 16 + (ln >> 5) * 8;
        const float* src = k + ((size_t)b * N_ + kvr) * D_ + d0;
        float4 a = *(const float4*)src;
        float4 c = *(const float4*)(src + 4);
        bf16x8 o;
        o[0] = (bf16)a.x; o[1] = (bf16)a.y; o[2] = (bf16)a.z; o[3] = (bf16)a.w;
        o[4] = (bf16)c.x; o[5] = (bf16)c.y; o[6] = (bf16)c.z; o[7] = (bf16)c.w;
        *(bf16x8*)(timg + t * 8) = o;
    }

    // --- V half phase 1: coalesced row load -> LDS bf16 ---
    {
        const int kv = t >> 3;                    // 0..63 (tile-local row)
        const int c8 = (t & 7) * 8;               // 0..56
        const float* src = v + ((size_t)b * N_ + T * 64 + kv) * D_ + c8;
        float4 a = *(const float4*)src;
        float4 c = *(const float4*)(src + 4);
        VT[kv][c8 + 0] = (bf16)a.x; VT[kv][c8 + 1] = (bf16)a.y;
        VT[kv][c8 + 2] = (bf16)a.z; VT[kv][c8 + 3] = (bf16)a.w;
        VT[kv][c8 + 4] = (bf16)c.x; VT[kv][c8 + 5] = (bf16)c.y;
        VT[kv][c8 + 6] = (bf16)c.z; VT[kv][c8 + 7] = (bf16)c.w;
    }
    __syncthreads();
    // --- V half phase 2: fragment-order read, coalesced store ---
    {
        const int d   = mt * 32 + (ln & 31);
        const int kv0 = ks * 16 + (ln >> 5) * 8;  // tile-local
        bf16x8 o;
        #pragma unroll
        for (int j = 0; j < 8; ++j) o[j] = VT[kv0 + j][d];
        *(bf16x8*)(timg + 4096 + t * 8) = o;
    }
}

static __device__ inline bf16x4 pack4(float a, float b, float c, float d) {
    bf16x4 r; r[0] = (bf16)a; r[1] = (bf16)b; r[2] = (bf16)c; r[3] = (bf16)d; return r;
}

// C->B half-wave exchange via v_permlane32_swap_b32. For (p,q) = swap(L,H):
//   p = {L.row0, H.row0}  == (half ? xhi : lo)
//   q = {L.row1, H.row1}  == (half ? hi  : xlo)
static __device__ inline bf16x8 cswap(bf16x4 lo, bf16x4 hi) {
    u32x2 l = __builtin_bit_cast(u32x2, lo);
    u32x2 h = __builtin_bit_cast(u32x2, hi);
    u32x2 r0 = __builtin_amdgcn_permlane32_swap(l[0], h[0], false, false);
    u32x2 r1 = __builtin_amdgcn_permlane32_swap(l[1], h[1], false, false);
    u32x4 o; o[0] = r0[0]; o[1] = r1[0]; o[2] = r0[1]; o[3] = r1[1];
    return __builtin_bit_cast(bf16x8, o);
}

// Flash attention, 32x32x16 MFMA, S^T/O^T orientation, P in registers.
//
// FINAL CHAMPION (= R8/R13: 82.5us attn, 152.5us total; reproduced 3x).
// One-tile software pipeline: body = { S-MFMAs(tile t) || softmax+PV(t-1) }
// so exp2 never depends on just-issued MFMAs; S results consumed a full
// iteration (~500cy) later. 3-slot LDS ring (mod-3: DMA write slot
// provably != both read slots).
//
// Session evidence (15 measured variants) -- sharp local optimum:
//  - software pipeline (this): -10% vs the ~90us plateau. The ONLY win.
//  - occupancy 8->16 w/CU: null. Free-running/no barriers: null.
//  - reg prefetch depth: -7%. setprio: -3%. ones-MFMA denominator: free
//    when barrier-locked, -8% here (contends the pipelined MFMA pipe).
//  - 1 S-chain: -6% (MFMA result latency needs 2 interleaved chains).
//  - PV chain split (+32 regs): -5% (occupancy). Body x2 (+state): -7%
//    (spill: FETCH 24.6->29.8MB). convert_kv 2-block split: null.
// Per-wave state exactly fills the 2-wave/SIMD register band; every
// perturbation loses on the register/occupancy/MFMA-contention triangle.
// NOT a hardware roofline (VALU 44%, no pipe saturated) -- the structural
// escape is an 8-wave co-designed rewrite (m214-class), out of scope here.
__global__ __launch_bounds__(256, 2) void attn_fwd(const float* __restrict__ q,
                                                   const bf16* __restrict__ img,
                                                   float* __restrict__ out) {
    __shared__ __align__(16) bf16 KV3[3][8192];   // 3-slot ring, 48 KB

    const int tid  = threadIdx.x;
    const int lane = tid & 63;
    const int wv   = tid >> 6;          // 0..3
    const int half = lane >> 5;
    const int l31  = lane & 31;

    const int bh = blockIdx.y;
    const int b  = bh >> 4;
    const int q0 = blockIdx.x * BM + wv * 32;

    const bf16* tiles = img + (size_t)b * 32 * 8192;

    // Q frags (B-layout for S^T: n=q=l31, k=d=ks*16+half*8+j), pre-scaled
    bf16x8 qf[4];
    #pragma unroll
    for (int ks = 0; ks < 4; ++ks) {
        const float* src = q + ((size_t)bh * N_ + q0 + l31) * D_ + ks * 16 + half * 8;
        float4 a = *(const float4*)src;
        float4 c = *(const float4*)(src + 4);
        bf16x8 pk;
        pk[0] = (bf16)(a.x * SCALE_LOG2E); pk[1] = (bf16)(a.y * SCALE_LOG2E);
        pk[2] = (bf16)(a.z * SCALE_LOG2E); pk[3] = (bf16)(a.w * SCALE_LOG2E);
        pk[4] = (bf16)(c.x * SCALE_LOG2E); pk[5] = (bf16)(c.y * SCALE_LOG2E);
        pk[6] = (bf16)(c.z * SCALE_LOG2E); pk[7] = (bf16)(c.w * SCALE_LOG2E);
        qf[ks] = pk;
    }

    f32x16 acc[2] = {{}, {}};           // O^T tiles [mt_d] (unnormalized)
    float lacc = 0.f;

    auto issue_dma = [&](int t, int sl) {
        const bf16* g = tiles + (size_t)t * 8192;
        #pragma unroll
        for (int j = 0; j < 4; ++j) {
            const int c = wv * 4 + j;             // 1 KB chunk 0..15
            __builtin_amdgcn_global_load_lds(GBL(g + c * 512 + lane * 8),
                                             LDS(&KV3[sl][c * 512]), 16, 0, 0);
        }
    };

    // S^T(tile it) = K Q^T into s: K frags JIT from ring slot it%3.
    // Two interleaved s-chains (R9: one chain = -5us).
    auto computeS = [&](int it, f32x16 (&s)[2]) {
        const bf16* bp = &KV3[it % 3][0];
        s[0] = f32x16{}; s[1] = f32x16{};
        #pragma unroll
        for (int ks = 0; ks < 4; ++ks) {
            bf16x8 k0 = *(const bf16x8*)&bp[((0 * 4 + ks) * 64 + lane) * 8];
            bf16x8 k1 = *(const bf16x8*)&bp[((1 * 4 + ks) * 64 + lane) * 8];
            s[0] = __builtin_amdgcn_mfma_f32_32x32x16_bf16(k0, qf[ks], s[0], 0, 0, 0);
            s[1] = __builtin_amdgcn_mfma_f32_32x32x16_bf16(k1, qf[ks], s[1], 0, 0, 0);
        }
    };
    // softmax + PV for tile it (V frags JIT from ring slot it%3).
    // Denominator on VALU (R11: ones-MFMA contends the pipelined MFMA pipe).
    auto softpv = [&](int it, const f32x16 (&s)[2]) {
        const bf16* vp = &KV3[it % 3][4096];
        #pragma unroll
        for (int mt = 0; mt < 2; ++mt) {
            #pragma unroll
            for (int sp = 0; sp < 2; ++sp) {
                const int g = mt * 2 + sp;        // kv k-step 0..3
                bf16x8 v0 = *(const bf16x8*)&vp[((0 * 4 + g) * 64 + lane) * 8];
                bf16x8 v1 = *(const bf16x8*)&vp[((1 * 4 + g) * 64 + lane) * 8];
                float pv8[8];
                #pragma unroll
                for (int r = 0; r < 8; ++r) pv8[r] = __builtin_amdgcn_exp2f(s[mt][8 * sp + r]);
                lacc += ((pv8[0] + pv8[1]) + (pv8[2] + pv8[3]))
                      + ((pv8[4] + pv8[5]) + (pv8[6] + pv8[7]));
                bf16x4 lo = pack4(pv8[0], pv8[1], pv8[2], pv8[3]);
                bf16x4 hi = pack4(pv8[4], pv8[5], pv8[6], pv8[7]);
                bf16x8 bfrag = cswap(lo, hi);
                acc[0] = __builtin_amdgcn_mfma_f32_32x32x16_bf16(v0, bfrag, acc[0], 0, 0, 0);
                acc[1] = __builtin_amdgcn_mfma_f32_32x32x16_bf16(v1, bfrag, acc[1], 0, 0, 0);
            }
        }
    };

    f32x16 sA[2], sB[2];

    // prologue: fill slot 0, start slot 1, compute S(0)
    issue_dma(0, 0);
    __syncthreads();                              // DMA(0) complete
    issue_dma(1, 1);
    computeS(0, sA);

    // pipelined main loop: pairs (it, it+1) for it = 1,3,...,29
    #pragma unroll 1
    for (int it = 1; it < 31; it += 2) {
        __syncthreads();                          // DMA(it) complete; prev reads done
        issue_dma(it + 1, (it + 1) % 3);          // overwrites tile it-2 (consumed)
        computeS(it, sB);                         // MFMA pipe: S(it)
        softpv(it - 1, sA);                       // VALU/trans+MFMA: tile it-1
        __syncthreads();                          // DMA(it+1) complete
        issue_dma(it + 2, (it + 2) % 3);          // it+2 <= 31
        computeS(it + 1, sA);
        softpv(it, sB);
    }
    // tail: S(31) + softmax(30), then softmax(31)
    __syncthreads();                              // DMA(31) complete
    computeS(31, sB);
    softpv(30, sA);
    softpv(31, sB);

    // epilogue: denominator = own + partner half-wave partial; store float4
    float l = lacc + __shfl_xor(lacc, 32);
    float inv = 1.0f / l;
    const int qrow = q0 + l31;
    float* dst = out + ((size_t)bh * N_ + qrow) * D_ + 4 * half;
    #pragma unroll
    for (int mt = 0; mt < 2; ++mt)
        #pragma unroll
        for (int rq = 0; rq < 4; ++rq) {
            float4 o;
            o.x = acc[mt][4 * rq + 0] * inv;
            o.y = acc[mt][4 * rq + 1] * inv;
            o.z = acc[mt][4 * rq + 2] * inv;
            o.w = acc[mt][4 * rq + 3] * inv;
            *(float4*)(dst + mt * 32 + 8 * rq) = o;   // d = mt*32 + 8*rq + 4*half
        }
}

extern "C" void kernel_launch(void* const* d_in, const int* in_sizes, int n_in,
                              void* d_out, int out_size, void* d_ws, size_t ws_size,
                              hipStream_t stream) {
    const float* q = (const float*)d_in[0];
    const float* k = (const float*)d_in[1];
    const float* v = (const float*)d_in[2];
    float* out = (float*)d_out;

    bf16* img = (bf16*)d_ws;                      // 128 tiles x 16 KB = 2 MB

    convert_kv<<<B_ * 32, 512, 0, stream>>>(k, v, img);
    dim3 grid(N_ / BM, B_ * H_);
    attn_fwd<<<grid, 256, 0, stream>>>(q, img, out);
}